// Round 12
// baseline (319.828 us; speedup 1.0000x reference)
//
#include <hip/hip_runtime.h>
#include <hip/hip_fp16.h>

#define D 128
#define H 4

typedef unsigned int uvec4 __attribute__((ext_vector_type(4)));

// ---------------------------------------------------------------------------
// Kernel 0: fast zero (hipMemsetAsync's fillBufferAligned measured 122us @ 10%
// occupancy for this buffer -- round-11 profile; this does it in ~2us).
// ---------------------------------------------------------------------------
__global__ void zero_kernel(int* __restrict__ p, int n) {
    int i = blockIdx.x * blockDim.x + threadIdx.x;
    if (i < n) p[i] = 0;
}

// ---------------------------------------------------------------------------
// Kernel 1 (fused): blocks [0,nbC) histogram src (4 edges/thread: int4 load,
// 4 independent returning atomics in flight, ushort4 rank store -- MLP=4 on
// the atomic path). Blocks [nbC, nbC+nbP) compute per-node projections ps/pd
// and the fp16 x-copy for gather. Count blocks FIRST (long pole starts t=0).
// ---------------------------------------------------------------------------
__global__ void proj_count_kernel(const float* __restrict__ x,
                                  const float* __restrict__ w,
                                  const float* __restrict__ attn,
                                  float* __restrict__ ps,
                                  float* __restrict__ pd,
                                  __half* __restrict__ xh,   // may be null
                                  const int* __restrict__ src,
                                  int* __restrict__ counts,
                                  unsigned short* __restrict__ rank,
                                  int N, int E, int nbC) {
    int bid = blockIdx.x;
    if (bid < nbC) {
        int e0 = (bid * 256 + threadIdx.x) * 4;
        if (e0 < E) {
            if (e0 + 4 <= E) {
                int4 s4 = *(const int4*)(src + e0);
                unsigned short r0 = (unsigned short)atomicAdd(counts + s4.x, 1);
                unsigned short r1 = (unsigned short)atomicAdd(counts + s4.y, 1);
                unsigned short r2 = (unsigned short)atomicAdd(counts + s4.z, 1);
                unsigned short r3 = (unsigned short)atomicAdd(counts + s4.w, 1);
                *(ushort4*)(rank + e0) = make_ushort4(r0, r1, r2, r3);
            } else {
                for (int e = e0; e < E; ++e)
                    rank[e] = (unsigned short)atomicAdd(counts + src[e], 1);
            }
        }
    } else {
        int node = (int)(((long long)(bid - nbC) * blockDim.x + threadIdx.x) >> 6);
        int lane = threadIdx.x & 63;
        if (node >= N) return;
        float x0 = x[(size_t)node * D + lane];
        float x1 = x[(size_t)node * D + 64 + lane];
        if (xh) {
            xh[(size_t)node * D + lane]      = __float2half(x0);
            xh[(size_t)node * D + 64 + lane] = __float2half(x1);
        }
#pragma unroll
        for (int h = 0; h < H; ++h) {
            float hv0 = x0 * w[h * D + lane];
            float hv1 = x1 * w[h * D + 64 + lane];
            float psv = hv0 * attn[h * 2 * D + lane]     + hv1 * attn[h * 2 * D + 64 + lane];
            float pdv = hv0 * attn[h * 2 * D + D + lane] + hv1 * attn[h * 2 * D + D + 64 + lane];
#pragma unroll
            for (int off = 32; off > 0; off >>= 1) {
                psv += __shfl_xor(psv, off);
                pdv += __shfl_xor(pdv, off);
            }
            if (lane == 0) {
                ps[(size_t)node * H + h] = psv;
                pd[(size_t)node * H + h] = pdv;
            }
        }
    }
}

// ---------------------------------------------------------------------------
// Scan pass 1: block-local exclusive scan of counts; block total to bsum.
// ---------------------------------------------------------------------------
__global__ void scan1_kernel(const int* __restrict__ counts,
                             int* __restrict__ offs,
                             int* __restrict__ bsum, int N) {
    __shared__ int wsum[16];
    __shared__ int woffi[16];
    int tid = threadIdx.x, lane = tid & 63, wid = tid >> 6;
    int i = blockIdx.x * 1024 + tid;
    int v = (i < N) ? counts[i] : 0;
    int acc = v;
#pragma unroll
    for (int d = 1; d < 64; d <<= 1) {
        int t = __shfl_up(acc, d);
        if (lane >= d) acc += t;
    }
    if (lane == 63) wsum[wid] = acc;
    __syncthreads();
    if (wid == 0) {
        int wv = (lane < 16) ? wsum[lane] : 0;
        int wacc = wv;
#pragma unroll
        for (int d = 1; d < 16; d <<= 1) {
            int t = __shfl_up(wacc, d);
            if (lane >= d) wacc += t;
        }
        if (lane < 16) woffi[lane] = wacc;
    }
    __syncthreads();
    int bexcl = (wid == 0) ? 0 : woffi[wid - 1];
    if (i < N) offs[i] = bexcl + (acc - v);
    if (tid == 0) bsum[blockIdx.x] = woffi[15];
}

// ---------------------------------------------------------------------------
// Scan pass 2: one wave scans block sums (supports nb <= 512).
// ---------------------------------------------------------------------------
__global__ void scan2_kernel(const int* __restrict__ bsum, int* __restrict__ boff, int nb) {
    int lane = threadIdx.x;
    int k = (nb + 63) >> 6;
    int local[8];
    int s = 0;
#pragma unroll 8
    for (int j = 0; j < k; ++j) {
        int idx = lane * k + j;
        local[j] = (idx < nb) ? bsum[idx] : 0;
        s += local[j];
    }
    int acc = s;
#pragma unroll
    for (int d = 1; d < 64; d <<= 1) {
        int t = __shfl_up(acc, d);
        if (lane >= d) acc += t;
    }
    int excl = acc - s;
#pragma unroll 8
    for (int j = 0; j < k; ++j) {
        int idx = lane * k + j;
        if (idx < nb) boff[idx] = excl;
        excl += local[j];
    }
}

// ---------------------------------------------------------------------------
// Scan pass 3: add block offsets; offs[N] = E.
// ---------------------------------------------------------------------------
__global__ void scan3_kernel(int* __restrict__ offs, const int* __restrict__ boff,
                             int N, int E) {
    int i = blockIdx.x * blockDim.x + threadIdx.x;
    if (i < N) offs[i] += boff[i >> 10];
    if (i == 0) offs[N] = E;
}

// ---------------------------------------------------------------------------
// Kernel 4: CSR scatter, atomic-free: pos = offs[src] + rank[e].
// Packs {dst, e01_fp16, e23_fp16} into ONE 16-byte record.
// ---------------------------------------------------------------------------
__global__ void scatter_kernel(const int* __restrict__ src, const int* __restrict__ dst,
                               const unsigned short* __restrict__ rank,
                               const int* __restrict__ offs,
                               const float* __restrict__ ps, const float* __restrict__ pd,
                               uint4* __restrict__ ec, int E) {
    int e = blockIdx.x * blockDim.x + threadIdx.x;
    if (e >= E) return;
    int s = src[e];
    int t = dst[e];
    int pos = offs[s] + (int)rank[e];
    const float4 ps4 = *(const float4*)(ps + (size_t)s * H);
    const float4 pd4 = *(const float4*)(pd + (size_t)t * H);
    float s0 = ps4.x + pd4.x; s0 = s0 > 0.f ? s0 : 0.2f * s0;
    float s1 = ps4.y + pd4.y; s1 = s1 > 0.f ? s1 : 0.2f * s1;
    float s2 = ps4.z + pd4.z; s2 = s2 > 0.f ? s2 : 0.2f * s2;
    float s3 = ps4.w + pd4.w; s3 = s3 > 0.f ? s3 : 0.2f * s3;
    union { __half2 h[2]; uint2 u; } pk;
    pk.h[0] = __floats2half2_rn(__expf(-s0), __expf(-s1));
    pk.h[1] = __floats2half2_rn(__expf(-s2), __expf(-s3));
    ec[pos] = make_uint4((unsigned)t, pk.u.x, pk.u.y, 0u);
}

// ---------------------------------------------------------------------------
// Kernel 5: per-node gather + fused normalize, 8-deep pipelined (MLP=8).
// XH=1: x rows read as fp16 (half request bytes). Plain cached loads/stores
// (round-9 NT hints regressed). Tail loop hand-written (round-7 lesson).
// ---------------------------------------------------------------------------
union HU { __half2 h; unsigned u; };

#define GDECL(j) uvec4 q##j; float2 v##j;
#define GLOAD(j) q##j = *((const uvec4*)ec + k + j);
#define GXLOADF(j) v##j = *(const float2*)(x + (size_t)q##j.x * D + lane2);
#define GXLOADH(j) { __half2 hv = *(const __half2*)(xh + (size_t)q##j.x * D + lane2); \
                     v##j = __half22float2(hv); }
#define GACC(j) { HU u01, u23; u01.u = q##j.y; u23.u = q##j.z;              \
    float e0 = __low2float(u01.h),  e1 = __high2float(u01.h);               \
    float e2 = __low2float(u23.h),  e3 = __high2float(u23.h);               \
    a0x += e0 * v##j.x; a0y += e0 * v##j.y; rs0 += e0;                      \
    a1x += e1 * v##j.x; a1y += e1 * v##j.y; rs1 += e1;                      \
    a2x += e2 * v##j.x; a2y += e2 * v##j.y; rs2 += e2;                      \
    a3x += e3 * v##j.x; a3y += e3 * v##j.y; rs3 += e3; }

template <int XH>
__global__ void gather_kernel(const float* __restrict__ x,
                              const __half* __restrict__ xh,
                              const float* __restrict__ w,
                              const int* __restrict__ offs,
                              const uint4* __restrict__ ec,
                              float* __restrict__ out,
                              int N, int nodeBeg, int nodeEnd) {
    int node = nodeBeg + (int)(((long long)blockIdx.x * blockDim.x + threadIdx.x) >> 6);
    int lane = threadIdx.x & 63;
    if (node >= nodeEnd) return;
    int lane2 = lane * 2;
    float a0x = 0, a0y = 0, a1x = 0, a1y = 0, a2x = 0, a2y = 0, a3x = 0, a3y = 0;
    float rs0 = 0, rs1 = 0, rs2 = 0, rs3 = 0;
    int beg = offs[node], end = offs[node + 1];
    int k = beg;
    for (; k + 8 <= end; k += 8) {
        GDECL(0) GDECL(1) GDECL(2) GDECL(3) GDECL(4) GDECL(5) GDECL(6) GDECL(7)
        GLOAD(0) GLOAD(1) GLOAD(2) GLOAD(3) GLOAD(4) GLOAD(5) GLOAD(6) GLOAD(7)
        if (XH) { GXLOADH(0) GXLOADH(1) GXLOADH(2) GXLOADH(3) GXLOADH(4) GXLOADH(5) GXLOADH(6) GXLOADH(7) }
        else    { GXLOADF(0) GXLOADF(1) GXLOADF(2) GXLOADF(3) GXLOADF(4) GXLOADF(5) GXLOADF(6) GXLOADF(7) }
        GACC(0) GACC(1) GACC(2) GACC(3) GACC(4) GACC(5) GACC(6) GACC(7)
    }
    for (; k < end; ++k) {                 // hand-written tail: index k ONLY
        uvec4 q = *((const uvec4*)ec + k);
        float2 v;
        if (XH) { __half2 hv = *(const __half2*)(xh + (size_t)q.x * D + lane2); v = __half22float2(hv); }
        else    { v = *(const float2*)(x + (size_t)q.x * D + lane2); }
        HU u01, u23; u01.u = q.y; u23.u = q.z;
        float e0 = __low2float(u01.h),  e1 = __high2float(u01.h);
        float e2 = __low2float(u23.h),  e3 = __high2float(u23.h);
        a0x += e0 * v.x; a0y += e0 * v.y; rs0 += e0;
        a1x += e1 * v.x; a1y += e1 * v.y; rs1 += e1;
        a2x += e2 * v.x; a2y += e2 * v.y; rs2 += e2;
        a3x += e3 * v.x; a3y += e3 * v.y; rs3 += e3;
    }
    float i0 = 1.0f / rs0, i1 = 1.0f / rs1, i2 = 1.0f / rs2, i3 = 1.0f / rs3;
    size_t nd = (size_t)N * D;
    size_t b = (size_t)node * D + lane2;
    const float2 w0 = *(const float2*)(w + 0 * D + lane2);
    const float2 w1 = *(const float2*)(w + 1 * D + lane2);
    const float2 w2 = *(const float2*)(w + 2 * D + lane2);
    const float2 w3 = *(const float2*)(w + 3 * D + lane2);
    *(float2*)(out + 0 * nd + b) = make_float2(a0x * w0.x * i0, a0y * w0.y * i0);
    *(float2*)(out + 1 * nd + b) = make_float2(a1x * w1.x * i1, a1y * w1.y * i1);
    *(float2*)(out + 2 * nd + b) = make_float2(a2x * w2.x * i2, a2y * w2.y * i2);
    *(float2*)(out + 3 * nd + b) = make_float2(a3x * w3.x * i3, a3y * w3.y * i3);
}

extern "C" void kernel_launch(void* const* d_in, const int* in_sizes, int n_in,
                              void* d_out, int out_size, void* d_ws, size_t ws_size,
                              hipStream_t stream) {
    const float* x    = (const float*)d_in[0];
    const float* w    = (const float*)d_in[1];
    const float* attn = (const float*)d_in[2];
    const int*   edge = (const int*)d_in[3];

    int N = in_sizes[0] / D;
    int E = in_sizes[3] / 2;
    const int* src = edge;
    const int* dst = edge + E;
    float* out = (float*)d_out;

    int nb = (N + 1023) / 1024;

    // Sizes (offs padded to N+2 ints so rank lands 8B-aligned for ushort4)
    size_t sz_ec     = (size_t)E * 16;
    size_t sz_xh     = (size_t)N * D * 2;
    size_t sz_psd    = (size_t)N * H * 4;       // each of ps, pd
    size_t sz_counts = (size_t)N * 4;
    size_t sz_offs   = ((size_t)N + 2) * 4;
    size_t sz_nb     = (size_t)((nb + 1) & ~1) * 4;
    size_t base_need = sz_ec + 2 * sz_psd + sz_counts + sz_offs + 2 * sz_nb
                     + (size_t)E * 2;           // rank (ushort)
    bool use_xh = ws_size >= base_need + sz_xh + 1024;

    char* wsp = (char*)d_ws;
    uint4* ec = (uint4*)wsp;            wsp += sz_ec;
    __half* xh = nullptr;
    if (use_xh) { xh = (__half*)wsp;    wsp += sz_xh; }
    float* ps     = (float*)wsp;        wsp += sz_psd;
    float* pd     = (float*)wsp;        wsp += sz_psd;
    int*   counts = (int*)wsp;          wsp += sz_counts;
    int*   offs   = (int*)wsp;          wsp += sz_offs;
    int*   bsum   = (int*)wsp;          wsp += sz_nb;
    int*   boff   = (int*)wsp;          wsp += sz_nb;
    unsigned short* rank = (unsigned short*)wsp;

    zero_kernel<<<(N + 255) / 256, 256, 0, stream>>>(counts, N);

    int nbC = (E + 1023) / 1024;     // count blocks: 4 edges/thread (first)
    int nbP = (N + 3) / 4;           // proj blocks
    proj_count_kernel<<<nbC + nbP, 256, 0, stream>>>(x, w, attn, ps, pd, xh, src,
                                                     counts, rank, N, E, nbC);
    scan1_kernel<<<nb, 1024, 0, stream>>>(counts, offs, bsum, N);
    scan2_kernel<<<1, 64, 0, stream>>>(bsum, boff, nb);
    scan3_kernel<<<(N + 255) / 256, 256, 0, stream>>>(offs, boff, N, E);
    scatter_kernel<<<(E + 255) / 256, 256, 0, stream>>>(src, dst, rank, offs,
                                                        ps, pd, ec, E);
    int half = N / 2;
    if (use_xh) {
        gather_kernel<1><<<(half + 3) / 4, 256, 0, stream>>>(x, xh, w, offs, ec, out, N, 0, half);
        gather_kernel<1><<<((N - half) + 3) / 4, 256, 0, stream>>>(x, xh, w, offs, ec, out, N, half, N);
    } else {
        gather_kernel<0><<<(half + 3) / 4, 256, 0, stream>>>(x, xh, w, offs, ec, out, N, 0, half);
        gather_kernel<0><<<((N - half) + 3) / 4, 256, 0, stream>>>(x, xh, w, offs, ec, out, N, half, N);
    }
}

// Round 14
// 314.075 us; speedup vs baseline: 1.0183x; 1.0183x over previous
//
#include <hip/hip_runtime.h>
#include <hip/hip_fp16.h>

#define D 128
#define H 4

typedef unsigned int uvec4 __attribute__((ext_vector_type(4)));

// ---------------------------------------------------------------------------
// Kernel 0: fast zero (hipMemsetAsync's fillBufferAligned measured 122us).
// ---------------------------------------------------------------------------
__global__ void zero_kernel(int* __restrict__ p, int n) {
    int i = blockIdx.x * blockDim.x + threadIdx.x;
    if (i < n) p[i] = 0;
}

// ---------------------------------------------------------------------------
// Kernel 1a: histogram of src with per-edge rank capture (returning atomic).
// Separate dispatch for profile attribution (was fused with proj).
// ---------------------------------------------------------------------------
__global__ void count_kernel(const int* __restrict__ src,
                             int* __restrict__ counts,
                             unsigned short* __restrict__ rank, int E) {
    int e = blockIdx.x * blockDim.x + threadIdx.x;
    if (e < E) rank[e] = (unsigned short)atomicAdd(counts + src[e], 1);
}

// ---------------------------------------------------------------------------
// Kernel 1b: per-node projections ps/pd + fp16 x-copy for gather.
// ---------------------------------------------------------------------------
__global__ void proj_kernel(const float* __restrict__ x,
                            const float* __restrict__ w,
                            const float* __restrict__ attn,
                            float* __restrict__ ps,
                            float* __restrict__ pd,
                            __half* __restrict__ xh,   // may be null
                            int N) {
    int node = (int)(((long long)blockIdx.x * blockDim.x + threadIdx.x) >> 6);
    int lane = threadIdx.x & 63;
    if (node >= N) return;
    float x0 = x[(size_t)node * D + lane];
    float x1 = x[(size_t)node * D + 64 + lane];
    if (xh) {
        xh[(size_t)node * D + lane]      = __float2half(x0);
        xh[(size_t)node * D + 64 + lane] = __float2half(x1);
    }
#pragma unroll
    for (int h = 0; h < H; ++h) {
        float hv0 = x0 * w[h * D + lane];
        float hv1 = x1 * w[h * D + 64 + lane];
        float psv = hv0 * attn[h * 2 * D + lane]     + hv1 * attn[h * 2 * D + 64 + lane];
        float pdv = hv0 * attn[h * 2 * D + D + lane] + hv1 * attn[h * 2 * D + D + 64 + lane];
#pragma unroll
        for (int off = 32; off > 0; off >>= 1) {
            psv += __shfl_xor(psv, off);
            pdv += __shfl_xor(pdv, off);
        }
        if (lane == 0) {
            ps[(size_t)node * H + h] = psv;
            pd[(size_t)node * H + h] = pdv;
        }
    }
}

// ---------------------------------------------------------------------------
// Scan pass 1: block-local exclusive scan of counts; block total to bsum.
// ---------------------------------------------------------------------------
__global__ void scan1_kernel(const int* __restrict__ counts,
                             int* __restrict__ offs,
                             int* __restrict__ bsum, int N) {
    __shared__ int wsum[16];
    __shared__ int woffi[16];
    int tid = threadIdx.x, lane = tid & 63, wid = tid >> 6;
    int i = blockIdx.x * 1024 + tid;
    int v = (i < N) ? counts[i] : 0;
    int acc = v;
#pragma unroll
    for (int d = 1; d < 64; d <<= 1) {
        int t = __shfl_up(acc, d);
        if (lane >= d) acc += t;
    }
    if (lane == 63) wsum[wid] = acc;
    __syncthreads();
    if (wid == 0) {
        int wv = (lane < 16) ? wsum[lane] : 0;
        int wacc = wv;
#pragma unroll
        for (int d = 1; d < 16; d <<= 1) {
            int t = __shfl_up(wacc, d);
            if (lane >= d) wacc += t;
        }
        if (lane < 16) woffi[lane] = wacc;
    }
    __syncthreads();
    int bexcl = (wid == 0) ? 0 : woffi[wid - 1];
    if (i < N) offs[i] = bexcl + (acc - v);
    if (tid == 0) bsum[blockIdx.x] = woffi[15];
}

// ---------------------------------------------------------------------------
// Scan pass 2: one wave scans block sums (supports nb <= 512).
// ---------------------------------------------------------------------------
__global__ void scan2_kernel(const int* __restrict__ bsum, int* __restrict__ boff, int nb) {
    int lane = threadIdx.x;
    int k = (nb + 63) >> 6;
    int local[8];
    int s = 0;
#pragma unroll 8
    for (int j = 0; j < k; ++j) {
        int idx = lane * k + j;
        local[j] = (idx < nb) ? bsum[idx] : 0;
        s += local[j];
    }
    int acc = s;
#pragma unroll
    for (int d = 1; d < 64; d <<= 1) {
        int t = __shfl_up(acc, d);
        if (lane >= d) acc += t;
    }
    int excl = acc - s;
#pragma unroll 8
    for (int j = 0; j < k; ++j) {
        int idx = lane * k + j;
        if (idx < nb) boff[idx] = excl;
        excl += local[j];
    }
}

// ---------------------------------------------------------------------------
// Scan pass 3: add block offsets; offs[N] = E.
// ---------------------------------------------------------------------------
__global__ void scan3_kernel(int* __restrict__ offs, const int* __restrict__ boff,
                             int N, int E) {
    int i = blockIdx.x * blockDim.x + threadIdx.x;
    if (i < N) offs[i] += boff[i >> 10];
    if (i == 0) offs[N] = E;
}

// ---------------------------------------------------------------------------
// Kernel 4: CSR scatter, atomic-free, 4 edges/thread (vectorized int4/ushort4
// loads; 4 independent ps/pd gathers + ec stores in flight).
// pos = offs[src] + rank[e]; record = {dst, e01_fp16, e23_fp16, 0}.
// ---------------------------------------------------------------------------
__device__ __forceinline__ void scatter_one(int s, int t, int rk,
                                            const int* __restrict__ offs,
                                            const float* __restrict__ ps,
                                            const float* __restrict__ pd,
                                            uvec4* __restrict__ ec) {
    int pos = offs[s] + rk;
    const float4 ps4 = *(const float4*)(ps + (size_t)s * H);
    const float4 pd4 = *(const float4*)(pd + (size_t)t * H);
    float s0 = ps4.x + pd4.x; s0 = s0 > 0.f ? s0 : 0.2f * s0;
    float s1 = ps4.y + pd4.y; s1 = s1 > 0.f ? s1 : 0.2f * s1;
    float s2 = ps4.z + pd4.z; s2 = s2 > 0.f ? s2 : 0.2f * s2;
    float s3 = ps4.w + pd4.w; s3 = s3 > 0.f ? s3 : 0.2f * s3;
    union { __half2 h[2]; uint2 u; } pk;
    pk.h[0] = __floats2half2_rn(__expf(-s0), __expf(-s1));
    pk.h[1] = __floats2half2_rn(__expf(-s2), __expf(-s3));
    uvec4 rec;
    rec.x = (unsigned)t; rec.y = pk.u.x; rec.z = pk.u.y; rec.w = 0u;
    ec[pos] = rec;
}

__global__ void scatter_kernel(const int* __restrict__ src, const int* __restrict__ dst,
                               const unsigned short* __restrict__ rank,
                               const int* __restrict__ offs,
                               const float* __restrict__ ps, const float* __restrict__ pd,
                               uvec4* __restrict__ ec, int E) {
    int e0 = (blockIdx.x * blockDim.x + threadIdx.x) * 4;
    if (e0 >= E) return;
    if (e0 + 4 <= E) {
        int4 s4 = *(const int4*)(src + e0);
        int4 t4 = *(const int4*)(dst + e0);
        ushort4 r4 = *(const ushort4*)(rank + e0);
        scatter_one(s4.x, t4.x, r4.x, offs, ps, pd, ec);
        scatter_one(s4.y, t4.y, r4.y, offs, ps, pd, ec);
        scatter_one(s4.z, t4.z, r4.z, offs, ps, pd, ec);
        scatter_one(s4.w, t4.w, r4.w, offs, ps, pd, ec);
    } else {
        for (int e = e0; e < E; ++e)
            scatter_one(src[e], dst[e], rank[e], offs, ps, pd, ec);
    }
}

// ---------------------------------------------------------------------------
// Kernel 5: per-node gather + fused normalize, 8-deep pipelined (MLP=8).
// XH=1: x rows read as fp16. Plain cached loads/stores (round-9 NT hints
// regressed). Tail loop hand-written (round-7 lesson).
// ---------------------------------------------------------------------------
union HU { __half2 h; unsigned u; };

#define GDECL(j) uvec4 q##j; float2 v##j;
#define GLOAD(j) q##j = *((const uvec4*)ec + k + j);
#define GXLOADF(j) v##j = *(const float2*)(x + (size_t)q##j.x * D + lane2);
#define GXLOADH(j) { __half2 hv = *(const __half2*)(xh + (size_t)q##j.x * D + lane2); \
                     v##j = __half22float2(hv); }
#define GACC(j) { HU u01, u23; u01.u = q##j.y; u23.u = q##j.z;              \
    float e0 = __low2float(u01.h),  e1 = __high2float(u01.h);               \
    float e2 = __low2float(u23.h),  e3 = __high2float(u23.h);               \
    a0x += e0 * v##j.x; a0y += e0 * v##j.y; rs0 += e0;                      \
    a1x += e1 * v##j.x; a1y += e1 * v##j.y; rs1 += e1;                      \
    a2x += e2 * v##j.x; a2y += e2 * v##j.y; rs2 += e2;                      \
    a3x += e3 * v##j.x; a3y += e3 * v##j.y; rs3 += e3; }

template <int XH>
__global__ void gather_kernel(const float* __restrict__ x,
                              const __half* __restrict__ xh,
                              const float* __restrict__ w,
                              const int* __restrict__ offs,
                              const uvec4* __restrict__ ec,
                              float* __restrict__ out,
                              int N, int nodeBeg, int nodeEnd) {
    int node = nodeBeg + (int)(((long long)blockIdx.x * blockDim.x + threadIdx.x) >> 6);
    int lane = threadIdx.x & 63;
    if (node >= nodeEnd) return;
    int lane2 = lane * 2;
    float a0x = 0, a0y = 0, a1x = 0, a1y = 0, a2x = 0, a2y = 0, a3x = 0, a3y = 0;
    float rs0 = 0, rs1 = 0, rs2 = 0, rs3 = 0;
    int beg = offs[node], end = offs[node + 1];
    int k = beg;
    for (; k + 8 <= end; k += 8) {
        GDECL(0) GDECL(1) GDECL(2) GDECL(3) GDECL(4) GDECL(5) GDECL(6) GDECL(7)
        GLOAD(0) GLOAD(1) GLOAD(2) GLOAD(3) GLOAD(4) GLOAD(5) GLOAD(6) GLOAD(7)
        if (XH) { GXLOADH(0) GXLOADH(1) GXLOADH(2) GXLOADH(3) GXLOADH(4) GXLOADH(5) GXLOADH(6) GXLOADH(7) }
        else    { GXLOADF(0) GXLOADF(1) GXLOADF(2) GXLOADF(3) GXLOADF(4) GXLOADF(5) GXLOADF(6) GXLOADF(7) }
        GACC(0) GACC(1) GACC(2) GACC(3) GACC(4) GACC(5) GACC(6) GACC(7)
    }
    for (; k < end; ++k) {                 // hand-written tail: index k ONLY
        uvec4 q = *((const uvec4*)ec + k);
        float2 v;
        if (XH) { __half2 hv = *(const __half2*)(xh + (size_t)q.x * D + lane2); v = __half22float2(hv); }
        else    { v = *(const float2*)(x + (size_t)q.x * D + lane2); }
        HU u01, u23; u01.u = q.y; u23.u = q.z;
        float e0 = __low2float(u01.h),  e1 = __high2float(u01.h);
        float e2 = __low2float(u23.h),  e3 = __high2float(u23.h);
        a0x += e0 * v.x; a0y += e0 * v.y; rs0 += e0;
        a1x += e1 * v.x; a1y += e1 * v.y; rs1 += e1;
        a2x += e2 * v.x; a2y += e2 * v.y; rs2 += e2;
        a3x += e3 * v.x; a3y += e3 * v.y; rs3 += e3;
    }
    float i0 = 1.0f / rs0, i1 = 1.0f / rs1, i2 = 1.0f / rs2, i3 = 1.0f / rs3;
    size_t nd = (size_t)N * D;
    size_t b = (size_t)node * D + lane2;
    const float2 w0 = *(const float2*)(w + 0 * D + lane2);
    const float2 w1 = *(const float2*)(w + 1 * D + lane2);
    const float2 w2 = *(const float2*)(w + 2 * D + lane2);
    const float2 w3 = *(const float2*)(w + 3 * D + lane2);
    *(float2*)(out + 0 * nd + b) = make_float2(a0x * w0.x * i0, a0y * w0.y * i0);
    *(float2*)(out + 1 * nd + b) = make_float2(a1x * w1.x * i1, a1y * w1.y * i1);
    *(float2*)(out + 2 * nd + b) = make_float2(a2x * w2.x * i2, a2y * w2.y * i2);
    *(float2*)(out + 3 * nd + b) = make_float2(a3x * w3.x * i3, a3y * w3.y * i3);
}

extern "C" void kernel_launch(void* const* d_in, const int* in_sizes, int n_in,
                              void* d_out, int out_size, void* d_ws, size_t ws_size,
                              hipStream_t stream) {
    const float* x    = (const float*)d_in[0];
    const float* w    = (const float*)d_in[1];
    const float* attn = (const float*)d_in[2];
    const int*   edge = (const int*)d_in[3];

    int N = in_sizes[0] / D;
    int E = in_sizes[3] / 2;
    const int* src = edge;
    const int* dst = edge + E;
    float* out = (float*)d_out;

    int nb = (N + 1023) / 1024;

    // Sizes (offs padded to N+2 ints so rank lands 8B-aligned for ushort4)
    size_t sz_ec     = (size_t)E * 16;
    size_t sz_xh     = (size_t)N * D * 2;
    size_t sz_psd    = (size_t)N * H * 4;       // each of ps, pd
    size_t sz_counts = (size_t)N * 4;
    size_t sz_offs   = ((size_t)N + 2) * 4;
    size_t sz_nb     = (size_t)((nb + 1) & ~1) * 4;
    size_t base_need = sz_ec + 2 * sz_psd + sz_counts + sz_offs + 2 * sz_nb
                     + (size_t)E * 2;           // rank (ushort)
    bool use_xh = ws_size >= base_need + sz_xh + 1024;

    char* wsp = (char*)d_ws;
    uvec4* ec = (uvec4*)wsp;            wsp += sz_ec;
    __half* xh = nullptr;
    if (use_xh) { xh = (__half*)wsp;    wsp += sz_xh; }
    float* ps     = (float*)wsp;        wsp += sz_psd;
    float* pd     = (float*)wsp;        wsp += sz_psd;
    int*   counts = (int*)wsp;          wsp += sz_counts;
    int*   offs   = (int*)wsp;          wsp += sz_offs;
    int*   bsum   = (int*)wsp;          wsp += sz_nb;
    int*   boff   = (int*)wsp;          wsp += sz_nb;
    unsigned short* rank = (unsigned short*)wsp;

    zero_kernel<<<(N + 255) / 256, 256, 0, stream>>>(counts, N);
    count_kernel<<<(E + 255) / 256, 256, 0, stream>>>(src, counts, rank, E);
    proj_kernel<<<(N + 3) / 4, 256, 0, stream>>>(x, w, attn, ps, pd, xh, N);
    scan1_kernel<<<nb, 1024, 0, stream>>>(counts, offs, bsum, N);
    scan2_kernel<<<1, 64, 0, stream>>>(bsum, boff, nb);
    scan3_kernel<<<(N + 255) / 256, 256, 0, stream>>>(offs, boff, N, E);
    scatter_kernel<<<(E + 1023) / 1024, 256, 0, stream>>>(src, dst, rank, offs,
                                                          ps, pd, ec, E);
    int half = N / 2;
    if (use_xh) {
        gather_kernel<1><<<(half + 3) / 4, 256, 0, stream>>>(x, xh, w, offs, ec, out, N, 0, half);
        gather_kernel<1><<<((N - half) + 3) / 4, 256, 0, stream>>>(x, xh, w, offs, ec, out, N, half, N);
    } else {
        gather_kernel<0><<<(half + 3) / 4, 256, 0, stream>>>(x, xh, w, offs, ec, out, N, 0, half);
        gather_kernel<0><<<((N - half) + 3) / 4, 256, 0, stream>>>(x, xh, w, offs, ec, out, N, half, N);
    }
}